// Round 2
// baseline (1694.398 us; speedup 1.0000x reference)
//
#include <hip/hip_runtime.h>
#include <math.h>

// FireflyVQ: down-conv x2 -> 9-stage RVQ (factored to 8-dim space) -> up-conv x2
// Shapes: B=8, C=512, T=8192, T'=2048, NQ=9, CBS=1024, CBD=8
// Output: x [8,512,8192] f32, codes [8,9,2048] (written as float), commit, cb.

constexpr int B_ = 8, C_ = 512, T_ = 8192;
constexpr int NQ = 9, CBS = 1024, CBD = 8;
constexpr int TQ = 2048;
constexpr int NTOK = B_ * TQ;   // 16384
#define EPSN 1e-12f

// ws layout (float offsets); total ~114.7 MB
constexpr size_t OFF_BUFA = 0;                         // 16777216  x1 / u1
constexpr size_t OFF_BUFB = OFF_BUFA + 16777216;       // 8388608   x2 / zq
constexpr size_t OFF_E0   = OFF_BUFB + 8388608;        // 1179648   e0 [n][72]
constexpr size_t OFF_Q    = OFF_E0 + 1179648;          // 1179648   Q [72][16384]
constexpr size_t OFF_WINN = OFF_Q + 1179648;           // 36864     WinN [72][512]
constexpr size_t OFF_WOUT = OFF_WINN + 36864;          // 36864     WoutS [512][72]
constexpr size_t OFF_UPWT = OFF_WOUT + 36864;          // 1048576   UpWt [2][1024][512]
constexpr size_t OFF_CBS  = OFF_UPWT + 1048576;        // 18432     [i][2][1024] (2/nrm, nsq)
constexpr size_t OFF_PT   = OFF_CBS + 18432;           // 2340      P tri blocks stride65
constexpr size_t OFF_BEFF = OFF_PT + 2340;             // 72
constexpr size_t OFF_BSUM = OFF_BEFF + 72;             // 512
constexpr size_t OFF_LOSS = OFF_BSUM + 512;            // 1024 block partials

// ---------------- prep kernels ----------------

__global__ void prep_upwt(const float* __restrict__ up_w, float* __restrict__ dst) {
  for (size_t idx = (size_t)blockIdx.x * 256 + threadIdx.x; idx < (size_t)2 * 1024 * 512;
       idx += (size_t)512 * 256) {
    int l = (int)(idx >> 19);
    int rem = (int)(idx & 524287);
    int m = rem >> 9;
    int i = rem & 511;
    dst[idx] = up_w[(((size_t)l * 512 + i) * 512 + (m >> 1)) * 2 + (m & 1)];
  }
}

__global__ void prep_small1(const float* __restrict__ in_v, const float* __restrict__ in_g,
                            const float* __restrict__ out_v, const float* __restrict__ out_g,
                            const float* __restrict__ out_b, const float* __restrict__ codebooks,
                            float* __restrict__ ws) {
  int bid = blockIdx.x, tid = threadIdx.x;
  if (bid < 18) {  // WinN: 72 rows, one wave each
    int wid = bid * 4 + (tid >> 6), lane = tid & 63;
    if (wid < 72) {
      const float* v = in_v + (size_t)wid * 512;
      float ss = 0.f;
      for (int c = lane; c < 512; c += 64) ss += v[c] * v[c];
      #pragma unroll
      for (int o = 32; o; o >>= 1) ss += __shfl_xor(ss, o);
      float sc = in_g[wid] / sqrtf(ss);
      float* dst = ws + OFF_WINN + (size_t)wid * 512;
      for (int c = lane; c < 512; c += 64) dst[c] = v[c] * sc;
    }
  } else if (bid < 36) {  // WoutS: 4608 rows of 8 -> [c][i*8+d]
    int r = (bid - 18) * 256 + tid;
    if (r < 4608) {
      int i = r >> 9, c = r & 511;
      const float* v = out_v + (size_t)r * 8;
      float ss = 0.f;
      #pragma unroll
      for (int d = 0; d < 8; d++) ss += v[d] * v[d];
      float sc = out_g[r] / sqrtf(ss);
      float* dst = ws + OFF_WOUT + (size_t)c * 72 + i * 8;
      #pragma unroll
      for (int d = 0; d < 8; d++) dst[d] = v[d] * sc;
    }
  } else if (bid < 72) {  // cbScal: 9216 rows
    int r = (bid - 36) * 256 + tid;
    if (r < 9216) {
      int i = r >> 10, j = r & 1023;
      const float* v = codebooks + (size_t)r * 8;
      float ss = 0.f;
      #pragma unroll
      for (int d = 0; d < 8; d++) ss += v[d] * v[d];
      float nm = fmaxf(sqrtf(ss), EPSN);
      float nsq = 0.f;
      #pragma unroll
      for (int d = 0; d < 8; d++) { float cn = v[d] / nm; nsq += cn * cn; }
      ws[OFF_CBS + ((size_t)i * 2 + 0) * 1024 + j] = 2.0f / nm;
      ws[OFF_CBS + ((size_t)i * 2 + 1) * 1024 + j] = nsq;
    }
  } else {  // biasSum: 512
    int c = (bid - 72) * 256 + tid;
    if (c < 512) {
      float s = 0.f;
      #pragma unroll
      for (int j = 0; j < 9; j++) s += out_b[j * 512 + c];
      ws[OFF_BSUM + c] = s;
    }
  }
}

__global__ void prep2(const float* __restrict__ in_b, const float* __restrict__ out_b,
                      float* __restrict__ ws) {
  int gw = blockIdx.x * 4 + (threadIdx.x >> 6), lane = threadIdx.x & 63;
  const float* WinN = ws + OFF_WINN;
  const float* WoutS = ws + OFF_WOUT;
  if (gw < 2304) {  // P entries: tri(ip,i) blocks of 64, row stride 65 in LDS layout
    int tri = gw >> 6, dd = gw & 63;
    int ip = 1;
    while (tri >= ip * (ip + 1) / 2) ip++;
    int i = tri - ip * (ip - 1) / 2;
    int d = dd >> 3, dp = dd & 7;
    const float* a = WinN + (size_t)(ip * 8 + d) * 512;
    float s = 0.f;
    for (int c = lane; c < 512; c += 64) s += a[c] * WoutS[(size_t)c * 72 + i * 8 + dp];
    #pragma unroll
    for (int o = 32; o; o >>= 1) s += __shfl_xor(s, o);
    if (lane == 0) ws[OFF_PT + (size_t)tri * 65 + dd] = s;
  } else if (gw < 2376) {  // beff
    int r = gw - 2304;
    int i = r >> 3;
    const float* a = WinN + (size_t)r * 512;
    float s = 0.f;
    for (int c = lane; c < 512; c += 64) {
      float ob = 0.f;
      for (int j = 0; j < i; j++) ob += out_b[j * 512 + c];
      s += a[c] * ob;
    }
    #pragma unroll
    for (int o = 32; o; o >>= 1) s += __shfl_xor(s, o);
    if (lane == 0) ws[OFF_BEFF + r] = in_b[r] - s;
  }
}

// ---------------- tiled f32 GEMM with gather/scatter modes ----------------
// GATHER: 0=DOWN (stride-2 conv gather), 1=BT (per-b [k][Tt]), 2=FLAT ([k][N])
// SCATTER: 0=NORM ([b][m][Tt]), 1=E0T ([n][M]), 2=UP (stride-2 transpose-conv scatter)
template <int GATHER, int SCATTER>
__global__ __launch_bounds__(256) void gemm_conv(const float* __restrict__ A,
                                                 const float* __restrict__ Bsrc,
                                                 const float* __restrict__ bias,
                                                 float* __restrict__ Out,
                                                 int M, int K, int N, int Tt) {
  constexpr int BM = 128, BN = 128, BK = 16;
  __shared__ float As[BK][BM + 4];
  __shared__ float Bs[BK][BN + 4];
  int tid = threadIdx.x;
  int tx = tid & 15, ty = tid >> 4;
  int n0 = blockIdx.x * BN, m0 = blockIdx.y * BM;
  int b = n0 / Tt, t0 = n0 % Tt;
  float acc[8][8];
  #pragma unroll
  for (int i = 0; i < 8; i++)
    #pragma unroll
    for (int j = 0; j < 8; j++) acc[i][j] = 0.f;

  for (int k0 = 0; k0 < K; k0 += BK) {
    // stage A (transposed to As[k][m])
    #pragma unroll
    for (int rep = 0; rep < 2; rep++) {
      int f = tid + rep * 256;
      int row = f >> 2, c4 = (f & 3) << 2;
      int m = m0 + row, k = k0 + c4;
      float4 v = make_float4(0.f, 0.f, 0.f, 0.f);
      if (m < M) {
        if (k + 3 < K) {
          v = *(const float4*)(A + (size_t)m * K + k);
        } else {
          float tmp[4] = {0.f, 0.f, 0.f, 0.f};
          for (int c = 0; c < 4; c++)
            if (k + c < K) tmp[c] = A[(size_t)m * K + k + c];
          v = make_float4(tmp[0], tmp[1], tmp[2], tmp[3]);
        }
      }
      As[c4 + 0][row] = v.x; As[c4 + 1][row] = v.y;
      As[c4 + 2][row] = v.z; As[c4 + 3][row] = v.w;
    }
    // stage B
    #pragma unroll
    for (int rep = 0; rep < 2; rep++) {
      int f = tid + rep * 256;
      int kk = f >> 5, n4 = (f & 31) << 2;
      int k = k0 + kk;
      float4 v;
      if (GATHER == 0) {
        int ich = k >> 1, k2 = k & 1;
        const float* p = Bsrc + ((size_t)(b * (K >> 1) + ich)) * (2 * Tt) + 2 * (t0 + n4);
        float4 lo = *(const float4*)p;
        float4 hi = *(const float4*)(p + 4);
        v = k2 ? make_float4(lo.y, lo.w, hi.y, hi.w) : make_float4(lo.x, lo.z, hi.x, hi.z);
      } else if (GATHER == 1) {
        v = *(const float4*)(Bsrc + ((size_t)(b * K + k)) * Tt + t0 + n4);
      } else {
        if (k < K) v = *(const float4*)(Bsrc + (size_t)k * N + n0 + n4);
        else v = make_float4(0.f, 0.f, 0.f, 0.f);
      }
      *(float4*)&Bs[kk][n4] = v;
    }
    __syncthreads();
    #pragma unroll
    for (int kk = 0; kk < BK; kk++) {
      float a[8], bb[8];
      *(float4*)&a[0] = *(float4*)&As[kk][ty * 8];
      *(float4*)&a[4] = *(float4*)&As[kk][ty * 8 + 4];
      *(float4*)&bb[0] = *(float4*)&Bs[kk][tx * 8];
      *(float4*)&bb[4] = *(float4*)&Bs[kk][tx * 8 + 4];
      #pragma unroll
      for (int i = 0; i < 8; i++)
        #pragma unroll
        for (int j = 0; j < 8; j++) acc[i][j] = fmaf(a[i], bb[j], acc[i][j]);
    }
    __syncthreads();
  }
  if (SCATTER == 0) {
    #pragma unroll
    for (int i = 0; i < 8; i++) {
      int m = m0 + ty * 8 + i;
      if (m < M) {
        float bv = bias ? bias[m] : 0.f;
        float* p = Out + ((size_t)(b * M + m)) * Tt + t0 + tx * 8;
        *(float4*)p = make_float4(acc[i][0] + bv, acc[i][1] + bv, acc[i][2] + bv, acc[i][3] + bv);
        *(float4*)(p + 4) = make_float4(acc[i][4] + bv, acc[i][5] + bv, acc[i][6] + bv, acc[i][7] + bv);
      }
    }
  } else if (SCATTER == 1) {
    #pragma unroll
    for (int j = 0; j < 8; j++) {
      int n = n0 + tx * 8 + j;
      int m = m0 + ty * 8;
      if (m < M) {
        float* p = Out + (size_t)n * M + m;
        if (m + 7 < M) {
          *(float4*)p = make_float4(acc[0][j], acc[1][j], acc[2][j], acc[3][j]);
          *(float4*)(p + 4) = make_float4(acc[4][j], acc[5][j], acc[6][j], acc[7][j]);
        } else {
          for (int i = 0; i < 8 && m + i < M; i++) p[i] = acc[i][j];
        }
      }
    }
  } else {
    // ConvTranspose scatter: acc rows i (even) and i+1 share o=m>>1 with k2=0/1
    // at adjacent time slots -> fuse into contiguous float2 stores.
    #pragma unroll
    for (int i = 0; i < 8; i += 2) {
      int m = m0 + ty * 8 + i;   // even
      int o = m >> 1;
      float bv = bias[o];
      float* rowp = Out + ((size_t)(b * (M >> 1) + o)) * (2 * Tt) + 2 * (t0 + tx * 8);
      #pragma unroll
      for (int j = 0; j < 8; j++) {
        *(float2*)(rowp + 2 * j) = make_float2(acc[i][j] + bv, acc[i + 1][j] + bv);
      }
    }
  }
}

// ---------------- RVQ core: 9 serial stages, all in 8-dim space ----------------
__global__ __launch_bounds__(256) void rvq_kernel(const float* __restrict__ codebooks,
                                                  const float* __restrict__ e0t,
                                                  const float* __restrict__ cbsW,
                                                  const float* __restrict__ ptW,
                                                  const float* __restrict__ beffW,
                                                  float* __restrict__ Qout,
                                                  float* __restrict__ codesOut,
                                                  float* __restrict__ lossPart) {
  __shared__ float cbv[8][1024];   // codebook column-major (conflict-free scan)
  __shared__ float cbs2[2][1024];  // [0]=2/nrm, [1]=nsq
  __shared__ float Pt[36 * 65];
  __shared__ float est[16][72];
  __shared__ float lred[4];
  int tid = threadIdx.x, wid = tid >> 6, lane = tid & 63;
  int nb0 = blockIdx.x * 16;
  for (int idx = tid; idx < 2340; idx += 256) Pt[idx] = ptW[idx];
  for (int idx = tid; idx < 16 * 72; idx += 256)
    est[idx / 72][idx % 72] = e0t[(size_t)nb0 * 72 + idx] + beffW[idx % 72];
  float lossLocal = 0.f;

  for (int i = 0; i < NQ; i++) {
    __syncthreads();
    const float* cbg = codebooks + (size_t)i * CBS * CBD;
    for (int lin = tid; lin < 2048; lin += 256) {
      int j = lin >> 1, half = (lin & 1) << 2;
      float4 v = *(const float4*)(cbg + (size_t)j * 8 + half);
      cbv[half + 0][j] = v.x; cbv[half + 1][j] = v.y;
      cbv[half + 2][j] = v.z; cbv[half + 3][j] = v.w;
    }
    for (int lin = tid; lin < 1024; lin += 256) {
      cbs2[0][lin] = cbsW[((size_t)i * 2 + 0) * 1024 + lin];
      cbs2[1][lin] = cbsW[((size_t)i * 2 + 1) * 1024 + lin];
    }
    __syncthreads();

    float ze[4][8], en[4][8];
    #pragma unroll
    for (int w = 0; w < 4; w++) {
      int tokl = wid * 4 + w;
      float ss = 0.f;
      #pragma unroll
      for (int d = 0; d < 8; d++) { float v = est[tokl][i * 8 + d]; ze[w][d] = v; ss += v * v; }
      float inv = 1.0f / fmaxf(sqrtf(ss), EPSN);
      #pragma unroll
      for (int d = 0; d < 8; d++) en[w][d] = ze[w][d] * inv;
    }
    float best[4]; int bidx[4];
    #pragma unroll
    for (int w = 0; w < 4; w++) { best[w] = -INFINITY; bidx[w] = 0; }
    #pragma unroll 4
    for (int r = 0; r < 16; r++) {
      int j = lane + (r << 6);
      float c0 = cbv[0][j], c1 = cbv[1][j], c2 = cbv[2][j], c3 = cbv[3][j];
      float c4 = cbv[4][j], c5 = cbv[5][j], c6 = cbv[6][j], c7 = cbv[7][j];
      float ti = cbs2[0][j], ns = cbs2[1][j];
      #pragma unroll
      for (int w = 0; w < 4; w++) {
        float dt = en[w][0] * c0;
        dt = fmaf(en[w][1], c1, dt); dt = fmaf(en[w][2], c2, dt);
        dt = fmaf(en[w][3], c3, dt); dt = fmaf(en[w][4], c4, dt);
        dt = fmaf(en[w][5], c5, dt); dt = fmaf(en[w][6], c6, dt);
        dt = fmaf(en[w][7], c7, dt);
        float s = fmaf(dt, ti, -ns);
        if (s > best[w]) { best[w] = s; bidx[w] = j; }
      }
    }
    #pragma unroll
    for (int w = 0; w < 4; w++) {
      #pragma unroll
      for (int off = 32; off; off >>= 1) {
        float so = __shfl_xor(best[w], off);
        int jo = __shfl_xor(bidx[w], off);
        if (so > best[w] || (so == best[w] && jo < bidx[w])) { best[w] = so; bidx[w] = jo; }
      }
    }
    int d = lane & 7;
    #pragma unroll
    for (int w = 0; w < 4; w++) {
      int jstar = bidx[w];
      int tokl = wid * 4 + w;
      int n = nb0 + tokl;
      float qd = cbv[d][jstar];
      float diff = ze[w][d] - qd;
      float sq = diff * diff;
      sq += __shfl_xor(sq, 1); sq += __shfl_xor(sq, 2); sq += __shfl_xor(sq, 4);
      if (lane == 0) lossLocal += sq;
      if (lane < 8) Qout[(size_t)(i * 8 + lane) * NTOK + n] = qd;
      if (lane == 0) codesOut[(size_t)((n >> 11) * NQ + i) * TQ + (n & (TQ - 1))] = (float)jstar;
      if (i < NQ - 1) {
        int f = lane >> 3, d2 = lane & 7;
        int ip = i + 1 + f;
        if (ip < NQ) {
          int tri = (ip * (ip - 1)) / 2 + i;
          const float* prow = &Pt[tri * 65 + d2 * 8];
          float s = 0.f;
          #pragma unroll
          for (int dp = 0; dp < 8; dp++) s = fmaf(prow[dp], cbv[dp][jstar], s);
          est[tokl][ip * 8 + d2] -= s;
        }
      }
    }
  }
  if (lane == 0) lred[wid] = lossLocal;
  __syncthreads();
  if (tid == 0) {
    float s = ((lred[0] + lred[1]) + lred[2]) + lred[3];
    lossPart[blockIdx.x] = s;
  }
}

__global__ void loss_fin(const float* __restrict__ lossPart, float* __restrict__ out) {
  __shared__ float s[256];
  int tid = threadIdx.x;
  float v = 0.f;
  for (int r = 0; r < 4; r++) v += lossPart[tid + r * 256];
  s[tid] = v;
  __syncthreads();
  for (int w = 128; w; w >>= 1) {
    if (tid < w) s[tid] += s[tid + w];
    __syncthreads();
  }
  if (tid == 0) {
    float total = s[0] / 131072.0f;  // B*CBD*T' = 8*8*2048
    out[0] = total;
    out[1] = total;  // commit_loss == cb_loss numerically
  }
}

// ---------------- launch ----------------
extern "C" void kernel_launch(void* const* d_in, const int* in_sizes, int n_in,
                              void* d_out, int out_size, void* d_ws, size_t ws_size,
                              hipStream_t stream) {
  const float* z      = (const float*)d_in[0];
  const float* down_w = (const float*)d_in[1];
  const float* down_b = (const float*)d_in[2];
  const float* up_w   = (const float*)d_in[3];
  const float* up_b   = (const float*)d_in[4];
  const float* in_v   = (const float*)d_in[5];
  const float* in_g   = (const float*)d_in[6];
  const float* in_b   = (const float*)d_in[7];
  const float* out_v  = (const float*)d_in[8];
  const float* out_g  = (const float*)d_in[9];
  const float* out_b  = (const float*)d_in[10];
  const float* codebooks = (const float*)d_in[11];
  float* ws = (float*)d_ws;
  float* xout = (float*)d_out;
  float* codesOut = xout + (size_t)B_ * C_ * T_;
  float* lossOut = codesOut + (size_t)B_ * NQ * TQ;

  hipLaunchKernelGGL(prep_upwt, dim3(512), dim3(256), 0, stream, up_w, ws + OFF_UPWT);
  hipLaunchKernelGGL(prep_small1, dim3(74), dim3(256), 0, stream,
                     in_v, in_g, out_v, out_g, out_b, codebooks, ws);
  hipLaunchKernelGGL(prep2, dim3(594), dim3(256), 0, stream, in_b, out_b, ws);
  // down1: [512,1024] @ gathered z -> x1 [8,512,4096]
  hipLaunchKernelGGL((gemm_conv<0, 0>), dim3(256, 4), dim3(256), 0, stream,
                     down_w, z, down_b, ws + OFF_BUFA, 512, 1024, 32768, 4096);
  // down2 -> x2 [8,512,2048]
  hipLaunchKernelGGL((gemm_conv<0, 0>), dim3(128, 4), dim3(256), 0, stream,
                     down_w + 524288, ws + OFF_BUFA, down_b + 512, ws + OFF_BUFB, 512, 1024, 16384, 2048);
  // e0 = WinN[72,512] @ x2, stored [n][72]
  hipLaunchKernelGGL((gemm_conv<1, 1>), dim3(128, 1), dim3(256), 0, stream,
                     ws + OFF_WINN, ws + OFF_BUFB, (const float*)nullptr, ws + OFF_E0, 72, 512, 16384, 2048);
  // RVQ: codes, Q, loss partials
  hipLaunchKernelGGL(rvq_kernel, dim3(1024), dim3(256), 0, stream,
                     codebooks, ws + OFF_E0, ws + OFF_CBS, ws + OFF_PT, ws + OFF_BEFF,
                     ws + OFF_Q, codesOut, ws + OFF_LOSS);
  // zq = WoutS[512,72] @ Q + biasSum -> [8,512,2048]
  hipLaunchKernelGGL((gemm_conv<2, 0>), dim3(128, 4), dim3(256), 0, stream,
                     ws + OFF_WOUT, ws + OFF_Q, ws + OFF_BSUM, ws + OFF_BUFB, 512, 72, 16384, 2048);
  // up1 -> u1 [8,512,4096]
  hipLaunchKernelGGL((gemm_conv<1, 2>), dim3(128, 8), dim3(256), 0, stream,
                     ws + OFF_UPWT, ws + OFF_BUFB, up_b, ws + OFF_BUFA, 1024, 512, 16384, 2048);
  // up2 -> x [8,512,8192] into d_out
  hipLaunchKernelGGL((gemm_conv<1, 2>), dim3(256, 8), dim3(256), 0, stream,
                     ws + OFF_UPWT + 524288, ws + OFF_BUFA, up_b + 512, xout, 1024, 512, 32768, 4096);
  hipLaunchKernelGGL(loss_fin, dim3(1), dim3(256), 0, stream, ws + OFF_LOSS, lossOut);
}

// Round 5
// 1324.550 us; speedup vs baseline: 1.2792x; 1.2792x over previous
//
#include <hip/hip_runtime.h>
#include <math.h>

// FireflyVQ hybrid R5: proven fp32 VALU path for code-determining GEMMs
// (down1/down2/e0) + split-bf16 MFMA for up1/up2 (x-only, loose threshold).
// Diagnostic: absmax ~0.008 => MFMA path correct; ~0.3-0.8 => gemmS logic bug.

using u16 = unsigned short;
typedef __attribute__((ext_vector_type(8))) short bf16x8;
typedef __attribute__((ext_vector_type(4))) short bf16x4;
typedef __attribute__((ext_vector_type(8))) u16 u16x8;
typedef __attribute__((ext_vector_type(4))) float f32x4;

constexpr int NQ = 9, CBS = 1024, CBD = 8;
constexpr int TQ = 2048;
constexpr int NTOK = 16384;
#define EPSN 1e-12f

// ---- ws layout (float offsets), total 28,669,804 fl (~109 MiB, == proven R2 size)
constexpr size_t OFF_X1   = 0;                        // x1 fp32 [8][512][4096]; us aliases later
constexpr size_t OFF_US   = OFF_X1;                   // us u16 2x[512][32768] (64MB)
constexpr size_t OFF_X2   = OFF_X1 + 16777216;        // x2 fp32 [8][512][2048]
constexpr size_t OFF_ZQS  = OFF_X2;                   // zqs u16 2x[512][16384] (alias, x2 dead after e0)
constexpr size_t OFF_E0T  = OFF_X2 + 8388608;         // e0t [16384][72]
constexpr size_t OFF_Q    = OFF_E0T + 1179648;        // Q [72][16384]
constexpr size_t OFF_UW1S = OFF_Q + 1179648;          // uw1 2 planes x 524288 u16
constexpr size_t OFF_UW2S = OFF_UW1S + 524288;
constexpr size_t OFF_WINN = OFF_UW2S + 524288;        // 36,864
constexpr size_t OFF_WOUT = OFF_WINN + 36864;         // 36,864
constexpr size_t OFF_CBS  = OFF_WOUT + 36864;         // 18,432
constexpr size_t OFF_PT   = OFF_CBS + 18432;          // 2,340
constexpr size_t OFF_BEFF = OFF_PT + 2340;            // 72
constexpr size_t OFF_BSUM = OFF_BEFF + 72;            // 512
constexpr size_t OFF_LOSS = OFF_BSUM + 512;           // 1,024

// ---------------- bf16 helpers ----------------
__device__ __forceinline__ u16 f2bf(float f) {
  unsigned u = __float_as_uint(f);
  u += 0x7FFFu + ((u >> 16) & 1u);
  return (u16)(u >> 16);
}
__device__ __forceinline__ float bf2f(u16 h) { return __uint_as_float(((unsigned)h) << 16); }
__device__ __forceinline__ void split2(float v, u16& a, u16& b) {
  a = f2bf(v); float r = v - bf2f(a);
  b = f2bf(r);
}

__device__ __forceinline__ void gload_lds16(const void* g, void* l) {
  __builtin_amdgcn_global_load_lds((const __attribute__((address_space(1))) unsigned*)g,
                                   (__attribute__((address_space(3))) unsigned*)l, 16, 0, 0);
}

// ---------------- prep kernels ----------------

// 2-split planes of ConvTranspose weights: uw[l] A[m=2o+kap][i2] = up_w[l][i2][o][kap]
__global__ void prep_upw(const float* __restrict__ up_w, float* __restrict__ ws) {
  int idx = blockIdx.x * 256 + threadIdx.x;   // [0, 2*524288)
  int mat = idx >> 19, e = idx & 524287;
  int m = e >> 9, i2 = e & 511, o = m >> 1, kap = m & 1;
  float v = up_w[(size_t)mat * 524288 + ((size_t)i2 * 512 + o) * 2 + kap];
  u16* dst = (u16*)(ws + (mat == 0 ? OFF_UW1S : OFF_UW2S));
  u16 s0, s1; split2(v, s0, s1);
  dst[e] = s0; dst[524288 + e] = s1;
}

__global__ void prep_small1(const float* __restrict__ in_v, const float* __restrict__ in_g,
                            const float* __restrict__ out_v, const float* __restrict__ out_g,
                            const float* __restrict__ out_b, const float* __restrict__ codebooks,
                            float* __restrict__ ws) {
  int bid = blockIdx.x, tid = threadIdx.x;
  if (bid < 18) {  // WinN: 72 rows, one wave each
    int wid = bid * 4 + (tid >> 6), lane = tid & 63;
    if (wid < 72) {
      const float* v = in_v + (size_t)wid * 512;
      float ss = 0.f;
      for (int c = lane; c < 512; c += 64) ss += v[c] * v[c];
      #pragma unroll
      for (int o = 32; o; o >>= 1) ss += __shfl_xor(ss, o);
      float sc = in_g[wid] / sqrtf(ss);
      float* dst = ws + OFF_WINN + (size_t)wid * 512;
      for (int c = lane; c < 512; c += 64) dst[c] = v[c] * sc;
    }
  } else if (bid < 36) {  // WoutS: 4608 rows of 8 -> [c][i*8+d]
    int r = (bid - 18) * 256 + tid;
    if (r < 4608) {
      int i = r >> 9, c = r & 511;
      const float* v = out_v + (size_t)r * 8;
      float ss = 0.f;
      #pragma unroll
      for (int d = 0; d < 8; d++) ss += v[d] * v[d];
      float sc = out_g[r] / sqrtf(ss);
      float* dst = ws + OFF_WOUT + (size_t)c * 72 + i * 8;
      #pragma unroll
      for (int d = 0; d < 8; d++) dst[d] = v[d] * sc;
    }
  } else if (bid < 72) {  // codebook scalars
    int r = (bid - 36) * 256 + tid;
    if (r < 9216) {
      int i = r >> 10, j = r & 1023;
      const float* v = codebooks + (size_t)r * 8;
      float ss = 0.f;
      #pragma unroll
      for (int d = 0; d < 8; d++) ss += v[d] * v[d];
      float nm = fmaxf(sqrtf(ss), EPSN);
      float nsq = 0.f;
      #pragma unroll
      for (int d = 0; d < 8; d++) { float cn = v[d] / nm; nsq += cn * cn; }
      ws[OFF_CBS + ((size_t)i * 2 + 0) * 1024 + j] = 2.0f / nm;
      ws[OFF_CBS + ((size_t)i * 2 + 1) * 1024 + j] = nsq;
    }
  } else {  // bias sum
    int c = (bid - 72) * 256 + tid;
    if (c < 512) {
      float s = 0.f;
      #pragma unroll
      for (int j = 0; j < 9; j++) s += out_b[j * 512 + c];
      ws[OFF_BSUM + c] = s;
    }
  }
}

__global__ void prep2(const float* __restrict__ in_b, const float* __restrict__ out_b,
                      float* __restrict__ ws) {
  int gw = blockIdx.x * 4 + (threadIdx.x >> 6), lane = threadIdx.x & 63;
  const float* WinN = ws + OFF_WINN;
  const float* WoutS = ws + OFF_WOUT;
  if (gw < 2304) {  // P tri blocks, row stride 65
    int tri = gw >> 6, dd = gw & 63;
    int ip = 1;
    while (tri >= ip * (ip + 1) / 2) ip++;
    int i = tri - ip * (ip - 1) / 2;
    int d = dd >> 3, dp = dd & 7;
    const float* a = WinN + (size_t)(ip * 8 + d) * 512;
    float s = 0.f;
    for (int c = lane; c < 512; c += 64) s += a[c] * WoutS[(size_t)c * 72 + i * 8 + dp];
    #pragma unroll
    for (int o = 32; o; o >>= 1) s += __shfl_xor(s, o);
    if (lane == 0) ws[OFF_PT + (size_t)tri * 65 + dd] = s;
  } else if (gw < 2376) {  // beff
    int r = gw - 2304;
    int i = r >> 3;
    const float* a = WinN + (size_t)r * 512;
    float s = 0.f;
    for (int c = lane; c < 512; c += 64) {
      float ob = 0.f;
      for (int j = 0; j < i; j++) ob += out_b[j * 512 + c];
      s += a[c] * ob;
    }
    #pragma unroll
    for (int o = 32; o; o >>= 1) s += __shfl_xor(s, o);
    if (lane == 0) ws[OFF_BEFF + r] = in_b[r] - s;
  }
}

// ---------------- proven fp32 tiled GEMM (R2 verbatim) ----------------
// GATHER: 0=DOWN (stride-2 conv gather), 1=BT (per-b [k][Tt])
// SCATTER: 0=NORM ([b][m][Tt]), 1=E0T ([n][M])
template <int GATHER, int SCATTER>
__global__ __launch_bounds__(256) void gemm_conv(const float* __restrict__ A,
                                                 const float* __restrict__ Bsrc,
                                                 const float* __restrict__ bias,
                                                 float* __restrict__ Out,
                                                 int M, int K, int N, int Tt) {
  constexpr int BM = 128, BN = 128, BK = 16;
  __shared__ float As[BK][BM + 4];
  __shared__ float Bs[BK][BN + 4];
  int tid = threadIdx.x;
  int tx = tid & 15, ty = tid >> 4;
  int n0 = blockIdx.x * BN, m0 = blockIdx.y * BM;
  int b = n0 / Tt, t0 = n0 % Tt;
  float acc[8][8];
  #pragma unroll
  for (int i = 0; i < 8; i++)
    #pragma unroll
    for (int j = 0; j < 8; j++) acc[i][j] = 0.f;

  for (int k0 = 0; k0 < K; k0 += BK) {
    #pragma unroll
    for (int rep = 0; rep < 2; rep++) {
      int f = tid + rep * 256;
      int row = f >> 2, c4 = (f & 3) << 2;
      int m = m0 + row, k = k0 + c4;
      float4 v = make_float4(0.f, 0.f, 0.f, 0.f);
      if (m < M) {
        if (k + 3 < K) {
          v = *(const float4*)(A + (size_t)m * K + k);
        } else {
          float tmp[4] = {0.f, 0.f, 0.f, 0.f};
          for (int c = 0; c < 4; c++)
            if (k + c < K) tmp[c] = A[(size_t)m * K + k + c];
          v = make_float4(tmp[0], tmp[1], tmp[2], tmp[3]);
        }
      }
      As[c4 + 0][row] = v.x; As[c4 + 1][row] = v.y;
      As[c4 + 2][row] = v.z; As[c4 + 3][row] = v.w;
    }
    #pragma unroll
    for (int rep = 0; rep < 2; rep++) {
      int f = tid + rep * 256;
      int kk = f >> 5, n4 = (f & 31) << 2;
      int k = k0 + kk;
      float4 v;
      if (GATHER == 0) {
        int ich = k >> 1, k2 = k & 1;
        const float* p = Bsrc + ((size_t)(b * (K >> 1) + ich)) * (2 * Tt) + 2 * (t0 + n4);
        float4 lo = *(const float4*)p;
        float4 hi = *(const float4*)(p + 4);
        v = k2 ? make_float4(lo.y, lo.w, hi.y, hi.w) : make_float4(lo.x, lo.z, hi.x, hi.z);
      } else {
        v = *(const float4*)(Bsrc + ((size_t)(b * K + k)) * Tt + t0 + n4);
      }
      *(float4*)&Bs[kk][n4] = v;
    }
    __syncthreads();
    #pragma unroll
    for (int kk = 0; kk < BK; kk++) {
      float a[8], bb[8];
      *(float4*)&a[0] = *(float4*)&As[kk][ty * 8];
      *(float4*)&a[4] = *(float4*)&As[kk][ty * 8 + 4];
      *(float4*)&bb[0] = *(float4*)&Bs[kk][tx * 8];
      *(float4*)&bb[4] = *(float4*)&Bs[kk][tx * 8 + 4];
      #pragma unroll
      for (int i = 0; i < 8; i++)
        #pragma unroll
        for (int j = 0; j < 8; j++) acc[i][j] = fmaf(a[i], bb[j], acc[i][j]);
    }
    __syncthreads();
  }
  if (SCATTER == 0) {
    #pragma unroll
    for (int i = 0; i < 8; i++) {
      int m = m0 + ty * 8 + i;
      if (m < M) {
        float bv = bias ? bias[m] : 0.f;
        float* p = Out + ((size_t)(b * M + m)) * Tt + t0 + tx * 8;
        *(float4*)p = make_float4(acc[i][0] + bv, acc[i][1] + bv, acc[i][2] + bv, acc[i][3] + bv);
        *(float4*)(p + 4) = make_float4(acc[i][4] + bv, acc[i][5] + bv, acc[i][6] + bv, acc[i][7] + bv);
      }
    }
  } else {
    #pragma unroll
    for (int j = 0; j < 8; j++) {
      int n = n0 + tx * 8 + j;
      int m = m0 + ty * 8;
      if (m < M) {
        float* p = Out + (size_t)n * M + m;
        if (m + 7 < M) {
          *(float4*)p = make_float4(acc[0][j], acc[1][j], acc[2][j], acc[3][j]);
          *(float4*)(p + 4) = make_float4(acc[4][j], acc[5][j], acc[6][j], acc[7][j]);
        } else {
          for (int i = 0; i < 8 && m + i < M; i++) p[i] = acc[i][j];
        }
      }
    }
  }
}

// ---------------- split-bf16 MFMA GEMM (up path only this round) ----------------
// B = NS u16 planes [K][N] via global_load_lds. Tile 128x64, BK=32, 4 waves (2x2).
// EPI: 3 = up1 2-split pair-store us[q][o][32768] + bias[o]
//      4 = final fp32 pair-store x[b][o][8192] + bias[o]
template <int NS, int EPI>
__global__ __launch_bounds__(256) void gemmS(const u16* __restrict__ Asp,
                                             const u16* __restrict__ Bp,
                                             const float* __restrict__ bias,
                                             float* __restrict__ OutF,
                                             u16* __restrict__ OutS,
                                             int K, int N, int aStride, int bStride) {
  __shared__ u16 As[NS * 4096];   // [NS][kc(4)][m(128)][8]
  __shared__ u16 Bs[NS * 2048];   // [NS][nt(4)][k(32)][16]
  const int tid = threadIdx.x;
  const int w = tid >> 6, l = tid & 63;
  const int g = l >> 4, li = l & 15;
  const int wr = w >> 1, wc = w & 1;
  const int n0 = blockIdx.x * 64, m0 = blockIdx.y * 128;

  f32x4 acc[4][2];
  #pragma unroll
  for (int a = 0; a < 4; a++)
    #pragma unroll
    for (int b = 0; b < 2; b++) acc[a][b] = (f32x4){0.f, 0.f, 0.f, 0.f};

  for (int k0 = 0; k0 < K; k0 += 32) {
    __syncthreads();
    #pragma unroll
    for (int p = 0; p < NS; ++p) {
      #pragma unroll
      for (int rep = 0; rep < 2; ++rep) {
        int i = tid + rep * 256;
        const u16* gp = Asp + (size_t)p * aStride + (size_t)(m0 + (i & 127)) * K + k0 + (i >> 7) * 8;
        gload_lds16(gp, &As[p * 4096 + i * 8]);
      }
    }
    #pragma unroll
    for (int q = 0; q < NS; ++q) {
      int i = tid;
      const u16* gb = Bp + (size_t)q * bStride + (size_t)(k0 + ((i >> 1) & 31)) * N +
                      n0 + (i >> 6) * 16 + (i & 1) * 8;
      gload_lds16(gb, &Bs[q * 2048 + i * 8]);
    }
    __syncthreads();

    // issue ALL tr-reads, then one wait + sched fence, THEN combine
    bf16x4 tA[2][NS], tB[2][NS];
    #pragma unroll
    for (int fn = 0; fn < 2; ++fn) {
      #pragma unroll
      for (int q = 0; q < NS; ++q) {
        unsigned ba = (unsigned)(uintptr_t)&Bs[q * 2048 + (wc * 2 + fn) * 512 + g * 128 + li];
        asm volatile("ds_read_b64_tr_b16 %0, %1" : "=&v"(tA[fn][q]) : "v"(ba));
        asm volatile("ds_read_b64_tr_b16 %0, %1 offset:128" : "=&v"(tB[fn][q]) : "v"(ba));
      }
    }
    asm volatile("s_waitcnt lgkmcnt(0)" ::: "memory");
    __builtin_amdgcn_sched_barrier(0);
    bf16x8 bfr[2][NS];
    #pragma unroll
    for (int fn = 0; fn < 2; ++fn)
      #pragma unroll
      for (int q = 0; q < NS; ++q)
        bfr[fn][q] = __builtin_shufflevector(tA[fn][q], tB[fn][q], 0, 1, 2, 3, 4, 5, 6, 7);

    #pragma unroll
    for (int fm = 0; fm < 4; ++fm) {
      bf16x8 afr[NS];
      #pragma unroll
      for (int p = 0; p < NS; ++p)
        afr[p] = *(const bf16x8*)&As[p * 4096 + (g * 128 + wr * 64 + fm * 16 + li) * 8];
      #pragma unroll
      for (int fn = 0; fn < 2; ++fn) {
        f32x4 a = acc[fm][fn];
        a = __builtin_amdgcn_mfma_f32_16x16x32_bf16(afr[0], bfr[fn][0], a, 0, 0, 0);
        a = __builtin_amdgcn_mfma_f32_16x16x32_bf16(afr[1], bfr[fn][0], a, 0, 0, 0);
        a = __builtin_amdgcn_mfma_f32_16x16x32_bf16(afr[0], bfr[fn][1], a, 0, 0, 0);
        if constexpr (NS == 3) {
          a = __builtin_amdgcn_mfma_f32_16x16x32_bf16(afr[2], bfr[fn][0], a, 0, 0, 0);
          a = __builtin_amdgcn_mfma_f32_16x16x32_bf16(afr[1], bfr[fn][1], a, 0, 0, 0);
          a = __builtin_amdgcn_mfma_f32_16x16x32_bf16(afr[0], bfr[fn][2], a, 0, 0, 0);
        }
        acc[fm][fn] = a;
      }
    }
  }

  const int mbase = m0 + wr * 64 + g * 4;
  const int nbase = n0 + wc * 32 + li;
  if constexpr (EPI == 3) {
    #pragma unroll
    for (int fm = 0; fm < 4; ++fm)
      #pragma unroll
      for (int fn = 0; fn < 2; ++fn) {
        int n = nbase + fn * 16;
        int n2 = (n >> 11) * 4096 + 2 * (n & 2047);
        #pragma unroll
        for (int rp = 0; rp < 2; ++rp) {
          int mm = mbase + fm * 16 + 2 * rp;
          int o = mm >> 1;
          float bv = bias[o];
          float v0 = acc[fm][fn][2 * rp] + bv, v1 = acc[fm][fn][2 * rp + 1] + bv;
          u16 a0, a1, b0, b1; split2(v0, a0, a1); split2(v1, b0, b1);
          *(unsigned*)&OutS[(size_t)o * 32768 + n2] = (unsigned)a0 | ((unsigned)b0 << 16);
          *(unsigned*)&OutS[16777216u + (size_t)o * 32768 + n2] = (unsigned)a1 | ((unsigned)b1 << 16);
        }
      }
  } else {  // EPI 4 final
    #pragma unroll
    for (int fm = 0; fm < 4; ++fm)
      #pragma unroll
      for (int fn = 0; fn < 2; ++fn) {
        int n = nbase + fn * 16;
        int b = n >> 12, t2 = n & 4095;
        #pragma unroll
        for (int rp = 0; rp < 2; ++rp) {
          int mm = mbase + fm * 16 + 2 * rp;
          int o = mm >> 1;
          float bv = bias[o];
          float2 st = make_float2(acc[fm][fn][2 * rp] + bv, acc[fm][fn][2 * rp + 1] + bv);
          *(float2*)&OutF[((size_t)(b * 512 + o)) * 8192 + 2 * t2] = st;
        }
      }
  }
}

// ---------------- zq: fp32 GEMM (K=72) with 2-split u16 plane output ----------------
__global__ __launch_bounds__(256) void gemm_zq(const float* __restrict__ A,     // WoutS [512][72]
                                               const float* __restrict__ Bsrc,  // Q [72][16384]
                                               const float* __restrict__ bsum,
                                               u16* __restrict__ zqs) {
  constexpr int K = 72, N = 16384;
  __shared__ float Ash[16][128 + 4];
  __shared__ float Bsh[16][128 + 4];
  int tid = threadIdx.x;
  int tx = tid & 15, ty = tid >> 4;
  int n0 = blockIdx.x * 128, m0 = blockIdx.y * 128;
  float acc[8][8];
  #pragma unroll
  for (int i = 0; i < 8; i++)
    #pragma unroll
    for (int j = 0; j < 8; j++) acc[i][j] = 0.f;

  for (int k0 = 0; k0 < K; k0 += 16) {
    #pragma unroll
    for (int rep = 0; rep < 2; rep++) {
      int f = tid + rep * 256;
      int row = f >> 2, c4 = (f & 3) << 2;
      int m = m0 + row, k = k0 + c4;
      float4 v = make_float4(0.f, 0.f, 0.f, 0.f);
      if (k + 3 < K) v = *(const float4*)(A + (size_t)m * K + k);
      else {
        float tmp[4] = {0.f, 0.f, 0.f, 0.f};
        for (int c = 0; c < 4; c++) if (k + c < K) tmp[c] = A[(size_t)m * K + k + c];
        v = make_float4(tmp[0], tmp[1], tmp[2], tmp[3]);
      }
      Ash[c4 + 0][row] = v.x; Ash[c4 + 1][row] = v.y;
      Ash[c4 + 2][row] = v.z; Ash[c4 + 3][row] = v.w;
    }
    #pragma unroll
    for (int rep = 0; rep < 2; rep++) {
      int f = tid + rep * 256;
      int kk = f >> 5, n4 = (f & 31) << 2;
      int k = k0 + kk;
      float4 v = make_float4(0.f, 0.f, 0.f, 0.f);
      if (k < K) v = *(const float4*)(Bsrc + (size_t)k * N + n0 + n4);
      *(float4*)&Bsh[kk][n4] = v;
    }
    __syncthreads();
    #pragma unroll
    for (int kk = 0; kk < 16; kk++) {
      float a[8], bb[8];
      *(float4*)&a[0] = *(float4*)&Ash[kk][ty * 8];
      *(float4*)&a[4] = *(float4*)&Ash[kk][ty * 8 + 4];
      *(float4*)&bb[0] = *(float4*)&Bsh[kk][tx * 8];
      *(float4*)&bb[4] = *(float4*)&Bsh[kk][tx * 8 + 4];
      #pragma unroll
      for (int i = 0; i < 8; i++)
        #pragma unroll
        for (int j = 0; j < 8; j++) acc[i][j] = fmaf(a[i], bb[j], acc[i][j]);
    }
    __syncthreads();
  }
  #pragma unroll
  for (int i = 0; i < 8; i++) {
    int m = m0 + ty * 8 + i;
    float bv = bsum[m];
    u16x8 q0, q1;
    #pragma unroll
    for (int j = 0; j < 8; j++) {
      u16 a, b; split2(acc[i][j] + bv, a, b);
      q0[j] = a; q1[j] = b;
    }
    *(u16x8*)&zqs[(size_t)m * 16384 + n0 + tx * 8] = q0;
    *(u16x8*)&zqs[8388608u + (size_t)m * 16384 + n0 + tx * 8] = q1;
  }
}

// ---------------- RVQ core (proven) ----------------
__global__ __launch_bounds__(256) void rvq_kernel(const float* __restrict__ codebooks,
                                                  const float* __restrict__ e0t,
                                                  const float* __restrict__ cbsW,
                                                  const float* __restrict__ ptW,
                                                  const float* __restrict__ beffW,
                                                  float* __restrict__ Qout,
                                                  float* __restrict__ codesOut,
                                                  float* __restrict__ lossPart) {
  __shared__ float cbv[8][1024];
  __shared__ float cbs2[2][1024];
  __shared__ float Pt[36 * 65];
  __shared__ float est[16][72];
  __shared__ float lred[4];
  int tid = threadIdx.x, wid = tid >> 6, lane = tid & 63;
  int nb0 = blockIdx.x * 16;
  for (int idx = tid; idx < 2340; idx += 256) Pt[idx] = ptW[idx];
  for (int idx = tid; idx < 16 * 72; idx += 256)
    est[idx / 72][idx % 72] = e0t[(size_t)nb0 * 72 + idx] + beffW[idx % 72];
  float lossLocal = 0.f;

  for (int i = 0; i < NQ; i++) {
    __syncthreads();
    const float* cbg = codebooks + (size_t)i * CBS * CBD;
    for (int lin = tid; lin < 2048; lin += 256) {
      int j = lin >> 1, half = (lin & 1) << 2;
      float4 v = *(const float4*)(cbg + (size_t)j * 8 + half);
      cbv[half + 0][j] = v.x; cbv[half + 1][j] = v.y;
      cbv[half + 2][j] = v.z; cbv[half + 3][j] = v.w;
    }
    for (int lin = tid; lin < 1024; lin += 256) {
      cbs2[0][lin] = cbsW[((size_t)i * 2 + 0) * 1024 + lin];
      cbs2[1][lin] = cbsW[((size_t)i * 2 + 1) * 1024 + lin];
    }
    __syncthreads();

    float ze[4][8], en[4][8];
    #pragma unroll
    for (int w = 0; w < 4; w++) {
      int tokl = wid * 4 + w;
      float ss = 0.f;
      #pragma unroll
      for (int d = 0; d < 8; d++) { float v = est[tokl][i * 8 + d]; ze[w][d] = v; ss += v * v; }
      float inv = 1.0f / fmaxf(sqrtf(ss), EPSN);
      #pragma unroll
      for (int d = 0; d < 8; d++) en[w][d] = ze[w][d] * inv;
    }
    float best[4]; int bidx[4];
    #pragma unroll
    for (int w = 0; w < 4; w++) { best[w] = -INFINITY; bidx[w] = 0; }
    #pragma unroll 4
    for (int r = 0; r < 16; r++) {
      int j = lane + (r << 6);
      float c0 = cbv[0][j], c1 = cbv[1][j], c2 = cbv[2][j], c3 = cbv[3][j];
      float c4 = cbv[4][j], c5 = cbv[5][j], c6 = cbv[6][j], c7 = cbv[7][j];
      float ti = cbs2[0][j], ns = cbs2[1][j];
      #pragma unroll
      for (int w = 0; w < 4; w++) {
        float dt = en[w][0] * c0;
        dt = fmaf(en[w][1], c1, dt); dt = fmaf(en[w][2], c2, dt);
        dt = fmaf(en[w][3], c3, dt); dt = fmaf(en[w][4], c4, dt);
        dt = fmaf(en[w][5], c5, dt); dt = fmaf(en[w][6], c6, dt);
        dt = fmaf(en[w][7], c7, dt);
        float s = fmaf(dt, ti, -ns);
        if (s > best[w]) { best[w] = s; bidx[w] = j; }
      }
    }
    #pragma unroll
    for (int w = 0; w < 4; w++) {
      #pragma unroll
      for (int off = 32; off; off >>= 1) {
        float so = __shfl_xor(best[w], off);
        int jo = __shfl_xor(bidx[w], off);
        if (so > best[w] || (so == best[w] && jo < bidx[w])) { best[w] = so; bidx[w] = jo; }
      }
    }
    int d = lane & 7;
    #pragma unroll
    for (int w = 0; w < 4; w++) {
      int jstar = bidx[w];
      int tokl = wid * 4 + w;
      int n = nb0 + tokl;
      float qd = cbv[d][jstar];
      float diff = ze[w][d] - qd;
      float sq = diff * diff;
      sq += __shfl_xor(sq, 1); sq += __shfl_xor(sq, 2); sq += __shfl_xor(sq, 4);
      if (lane == 0) lossLocal += sq;
      if (lane < 8) Qout[(size_t)(i * 8 + lane) * NTOK + n] = qd;
      if (lane == 0) codesOut[(size_t)((n >> 11) * NQ + i) * TQ + (n & (TQ - 1))] = (float)jstar;
      if (i < NQ - 1) {
        int f = lane >> 3, d2 = lane & 7;
        int ip = i + 1 + f;
        if (ip < NQ) {
          int tri = (ip * (ip - 1)) / 2 + i;
          const float* prow = &Pt[tri * 65 + d2 * 8];
          float s = 0.f;
          #pragma unroll
          for (int dp = 0; dp < 8; dp++) s = fmaf(prow[dp], cbv[dp][jstar], s);
          est[tokl][ip * 8 + d2] -= s;
        }
      }
    }
  }
  if (lane == 0) lred[wid] = lossLocal;
  __syncthreads();
  if (tid == 0) {
    float s = ((lred[0] + lred[1]) + lred[2]) + lred[3];
    lossPart[blockIdx.x] = s;
  }
}

__global__ void loss_fin(const float* __restrict__ lossPart, float* __restrict__ out) {
  __shared__ float s[256];
  int tid = threadIdx.x;
  float v = 0.f;
  for (int r = 0; r < 4; r++) v += lossPart[tid + r * 256];
  s[tid] = v;
  __syncthreads();
  for (int w = 128; w; w >>= 1) {
    if (tid < w) s[tid] += s[tid + w];
    __syncthreads();
  }
  if (tid == 0) {
    float total = s[0] / 131072.0f;
    out[0] = total;
    out[1] = total;
  }
}

// ---------------- launch ----------------
extern "C" void kernel_launch(void* const* d_in, const int* in_sizes, int n_in,
                              void* d_out, int out_size, void* d_ws, size_t ws_size,
                              hipStream_t stream) {
  const float* z      = (const float*)d_in[0];
  const float* down_w = (const float*)d_in[1];
  const float* down_b = (const float*)d_in[2];
  const float* up_w   = (const float*)d_in[3];
  const float* up_b   = (const float*)d_in[4];
  const float* in_v   = (const float*)d_in[5];
  const float* in_g   = (const float*)d_in[6];
  const float* in_b   = (const float*)d_in[7];
  const float* out_v  = (const float*)d_in[8];
  const float* out_g  = (const float*)d_in[9];
  const float* out_b  = (const float*)d_in[10];
  const float* codebooks = (const float*)d_in[11];
  float* ws = (float*)d_ws;
  float* xout = (float*)d_out;
  float* codesOut = xout + (size_t)8 * 512 * 8192;
  float* lossOut = codesOut + (size_t)8 * NQ * TQ;

  hipLaunchKernelGGL(prep_upw, dim3(4096), dim3(256), 0, stream, up_w, ws);
  hipLaunchKernelGGL(prep_small1, dim3(74), dim3(256), 0, stream,
                     in_v, in_g, out_v, out_g, out_b, codebooks, ws);
  hipLaunchKernelGGL(prep2, dim3(594), dim3(256), 0, stream, in_b, out_b, ws);
  // down1 (fp32): [512,1024] @ gathered z -> x1 [8,512,4096]
  hipLaunchKernelGGL((gemm_conv<0, 0>), dim3(256, 4), dim3(256), 0, stream,
                     down_w, z, down_b, ws + OFF_X1, 512, 1024, 32768, 4096);
  // down2 (fp32) -> x2 [8,512,2048]
  hipLaunchKernelGGL((gemm_conv<0, 0>), dim3(128, 4), dim3(256), 0, stream,
                     down_w + 524288, ws + OFF_X1, down_b + 512, ws + OFF_X2, 512, 1024, 16384, 2048);
  // e0 (fp32) = WinN[72,512] @ x2 -> e0t [16384][72]
  hipLaunchKernelGGL((gemm_conv<1, 1>), dim3(128, 1), dim3(256), 0, stream,
                     ws + OFF_WINN, ws + OFF_X2, (const float*)nullptr, ws + OFF_E0T, 72, 512, 16384, 2048);
  // RVQ
  hipLaunchKernelGGL(rvq_kernel, dim3(1024), dim3(256), 0, stream,
                     codebooks, ws + OFF_E0T, ws + OFF_CBS, ws + OFF_PT, ws + OFF_BEFF,
                     ws + OFF_Q, codesOut, ws + OFF_LOSS);
  // zq (fp32, K=72) -> 2-split u16 planes zqs [2][512][16384]
  hipLaunchKernelGGL(gemm_zq, dim3(128, 4), dim3(256), 0, stream,
                     ws + OFF_WOUT, ws + OFF_Q, ws + OFF_BSUM, (u16*)(ws + OFF_ZQS));
  // up1 (MFMA 2-split): A=uw1s [1024][512], B=zqs -> us 2-split planes [2][512][32768]
  hipLaunchKernelGGL((gemmS<2, 3>), dim3(256, 8), dim3(256), 0, stream,
                     (const u16*)(ws + OFF_UW1S), (const u16*)(ws + OFF_ZQS), up_b,
                     (float*)nullptr, (u16*)(ws + OFF_US), 512, 16384, 524288, 8388608);
  // up2 (MFMA 2-split): A=uw2s, B=us -> x fp32 to d_out
  hipLaunchKernelGGL((gemmS<2, 4>), dim3(512, 8), dim3(256), 0, stream,
                     (const u16*)(ws + OFF_UW2S), (const u16*)(ws + OFF_US), up_b + 512,
                     xout, (u16*)nullptr, 512, 32768, 524288, 16777216);
  hipLaunchKernelGGL(loss_fin, dim3(1), dim3(256), 0, stream, ws + OFF_LOSS, lossOut);
}